// Round 9
// baseline (244.963 us; speedup 1.0000x reference)
//
#include <hip/hip_runtime.h>

#define NROWS 4096
#define DIM   1024
#define NT    528   // triangular 32x32 tile grid

using f32x4 = __attribute__((ext_vector_type(4))) float;
using bfrag = __attribute__((ext_vector_type(8))) short;
typedef unsigned long long u64;

__device__ __forceinline__ unsigned short f2bf(float f) {
  unsigned u = __float_as_uint(f);
  u += 0x7fffu + ((u >> 16) & 1u);
  return (unsigned short)(u >> 16);
}
__device__ __forceinline__ float bf2f(unsigned short b) {
  return __uint_as_float(((unsigned)b) << 16);
}
__device__ __forceinline__ u64 shflx64(u64 v, int m) {
  int lo = __shfl_xor((int)(unsigned)(v & 0xffffffffull), m);
  int hi = __shfl_xor((int)(unsigned)(v >> 32), m);
  return ((u64)(unsigned)hi << 32) | (unsigned)lo;
}

// fp32 -> bf16 (RNE) + row squared-norms (+ out zero)
__global__ void prep_kernel(const float* __restrict__ X, unsigned short* __restrict__ Xb,
                            float* __restrict__ sqv, float* out) {
  int row = blockIdx.x, t = threadIdx.x;  // 256 threads, 4 floats each
  float4 v = reinterpret_cast<const float4*>(X + (size_t)row * DIM)[t];
  unsigned short b0 = f2bf(v.x), b1 = f2bf(v.y), b2 = f2bf(v.z), b3 = f2bf(v.w);
  float f0 = bf2f(b0), f1 = bf2f(b1), f2 = bf2f(b2), f3 = bf2f(b3);
  float s = f0 * f0 + f1 * f1 + f2 * f2 + f3 * f3;
  reinterpret_cast<ushort4*>(Xb + (size_t)row * DIM)[t] = make_ushort4(b0, b1, b2, b3);
  for (int m = 32; m; m >>= 1) s += __shfl_xor(s, m);
  __shared__ float ws4[4];
  if ((t & 63) == 0) ws4[t >> 6] = s;
  __syncthreads();
  if (t == 0) {
    sqv[row] = (ws4[0] + ws4[1]) + (ws4[2] + ws4[3]);
    if (row == 0) out[0] = 0.f;
  }
}

// Stage one BK=32 tile pair into BASE (A [128][32] at +0, B at +8192).
// Each load: 16 contiguous rows x 64B (coalesced 1KB). 2-bit k-slot XOR
// involution (rule 21): LDS[r][slot] holds global k-slot slot^(r&3); linear
// LDS dest, inverse-swizzled global source. 8 loads per wave (A:4, B:4).
#define STAGE(BASE, KS)                                                          \
  {                                                                              \
    _Pragma("unroll")                                                            \
    for (int jj = 0; jj < 4; ++jj) {                                             \
      int ch = wave * 4 + jj;                   /* chunk of 16 rows */           \
      int boff = ch * 1024;                                                      \
      int rr = ch * 16 + (lane >> 2);           /* row this lane fills */        \
      const unsigned short* sA = Xb + (size_t)(row0 + rr) * DIM + (KS) + ksrc;   \
      __builtin_amdgcn_global_load_lds(                                          \
          (const __attribute__((address_space(1))) void*)sA,                     \
          (__attribute__((address_space(3))) void*)((BASE) + boff), 16, 0, 0);   \
      const unsigned short* sB = Xb + (size_t)(col0 + rr) * DIM + (KS) + ksrc;   \
      __builtin_amdgcn_global_load_lds(                                          \
          (const __attribute__((address_space(1))) void*)sB,                     \
          (__attribute__((address_space(3))) void*)((BASE) + 8192 + boff), 16, 0, 0); \
    }                                                                            \
  }

// One BK=32 compute step from BASE: 12 ds_read_b128 (uniform banks) + 32 MFMA.
// Wave owns OUTPUT rows [wave*64, +64) x all 128 cols. Same lane->k map for
// A and B (Gram-safe).
#define BODY(BASE)                                                              \
  {                                                                             \
    unsigned short(*As_)[32] = (unsigned short(*)[32])(BASE);                   \
    unsigned short(*Bs_)[32] = (unsigned short(*)[32])((BASE) + 8192);          \
    bfrag a[4], b[8];                                                           \
    int kel = (q ^ (li & 3)) * 8;                                               \
    _Pragma("unroll") for (int m = 0; m < 4; ++m)                               \
      a[m] = *(const bfrag*)&As_[wr + m * 16 + li][kel];                        \
    _Pragma("unroll") for (int n = 0; n < 8; ++n)                               \
      b[n] = *(const bfrag*)&Bs_[n * 16 + li][kel];                             \
    _Pragma("unroll") for (int m = 0; m < 4; ++m)                               \
      _Pragma("unroll") for (int n = 0; n < 8; ++n)                             \
        acc[m][n] = __builtin_amdgcn_mfma_f32_16x16x32_bf16(a[m], b[n], acc[m][n], 0, 0, 0); \
  }

// 128x128 bf16-MFMA Gram tile, 2 waves, BK=32 double-buffered with COUNTED
// vmcnt (never drained in-loop, T3/T4) + raw s_barrier. Fused masked
// reductions; commit via LDS single-writer tables -> coalesced P* stores.
__global__ __launch_bounds__(128, 2) void gram_kernel(
    const unsigned short* __restrict__ Xb, const float* __restrict__ sqv,
    const int* __restrict__ tg, const int* __restrict__ fl,
    float* __restrict__ PmS, float* __restrict__ PmD,
    u64* __restrict__ PnS, u64* __restrict__ PnD) {
  __shared__ __attribute__((aligned(16))) char smem[32768];  // 2 x (A8K|B8K); tabs alias
  __shared__ float srow[128], scol[128];
  __shared__ int rtagp[128], ctagp[128];

  // triangular decode (tm-major): tiles with tm <= tn; g == blockIdx.x
  int tm = 0, g = blockIdx.x, rem = 32;
  while (g >= rem) { g -= rem; rem--; tm++; }
  int tn = tm + g;
  const int row0 = tm * 128, col0 = tn * 128;
  const int tid = threadIdx.x;
  const int wave = tid >> 6, lane = tid & 63;
  const int q = lane >> 4, li = lane & 15;
  // staging source k-offset: global slot = (lane&3) ^ (row&3), row&3=(lane>>2)&3
  const int ksrc = ((lane & 3) ^ ((lane >> 2) & 3)) * 8;

  char* B0 = smem;
  char* B1 = smem + 16384;

  STAGE(B0, 0);
  STAGE(B1, 32);
  srow[tid] = sqv[row0 + tid];
  rtagp[tid] = (fl[row0 + tid] << 12) | tg[row0 + tid];  // tg<1024, fl in {0,1}
  scol[tid] = sqv[col0 + tid];
  ctagp[tid] = (fl[col0 + tid] << 12) | tg[col0 + tid];

  const int wr = wave * 64;
  f32x4 acc[4][8] = {};

  // main loop: 31 steps with counted vmcnt(8); tail drains.
  for (int tt = 0; tt < 31; ++tt) {
    asm volatile("s_waitcnt vmcnt(8)" ::: "memory");  // own cur-batch done
    __builtin_amdgcn_s_barrier();                     // partner's cur-batch done too
    if (tt & 1) { BODY(B1); } else { BODY(B0); }
    asm volatile("s_waitcnt lgkmcnt(0)" ::: "memory");  // my ds_reads of cur retired
    __builtin_amdgcn_s_barrier();                     // both waves done reading cur
    if (tt < 30) {
      if (tt & 1) { STAGE(B1, (tt + 2) * 32); } else { STAGE(B0, (tt + 2) * 32); }
    }
  }
  asm volatile("s_waitcnt vmcnt(0)" ::: "memory");
  __builtin_amdgcn_s_barrier();
  BODY(B1);  // tt=31 is odd
  __syncthreads();  // all K-loop LDS reads done before tables alias smem

  // LDS partial tables (single-writer slots, no atomics):
  // rows [0,128): complete within one wave -> direct write.
  // cols [128, 128+256): slot = 128 + lc*2 + wave, merged below.
  float* tab_mS = (float*)smem;                  // 1.5 KB
  float* tab_mD = (float*)(smem + 2048);         // 1.5 KB
  u64*   tab_nS = (u64*)(smem + 4096);           // 3 KB
  u64*   tab_nD = (u64*)(smem + 8192);           // 3 KB

  float cmxS[8], cmxD[8];
  u64 cmnS[8], cmnD[8];
  int ctv[8]; float scv[8];
#pragma unroll
  for (int n = 0; n < 8; ++n) {
    cmxS[n] = -1.f; cmxD[n] = -1.f; cmnS[n] = ~0ull; cmnD[n] = ~0ull;
    int lc = n * 16 + li; ctv[n] = ctagp[lc]; scv[n] = scol[lc];
  }
#pragma unroll
  for (int m = 0; m < 4; ++m)
#pragma unroll
    for (int r = 0; r < 4; ++r) {
      int lr = wr + m * 16 + q * 4 + r;   // C/D layout (m89-verified)
      int rt = rtagp[lr];
      float sr = srow[lr];
      u64 rbase = (unsigned)(row0 + lr);
      float rmxS = -1.f, rmxD = -1.f;
      u64 rmnS = ~0ull, rmnD = ~0ull;
#pragma unroll
      for (int n = 0; n < 8; ++n) {
        float d = sqrtf(fmaxf(sr + scv[n] - 2.0f * acc[m][n][r], 1e-12f));
        int x = rt ^ ctv[n];
        u64 db = (u64)__float_as_uint(d) << 32;
        u64 pkr = db | (unsigned)(col0 + n * 16 + li);
        u64 pkc = db | rbase;
        if ((x & 0xFFF) == 0) {
          if ((x >> 12) == 0) { rmxS = fmaxf(rmxS, d); cmxS[n] = fmaxf(cmxS[n], d); }
          else                { rmxD = fmaxf(rmxD, d); cmxD[n] = fmaxf(cmxD[n], d); }
        } else {
          if ((x >> 12) == 0) { if (pkr < rmnS) rmnS = pkr; if (pkc < cmnS[n]) cmnS[n] = pkc; }
          else                { if (pkr < rmnD) rmnD = pkr; if (pkc < cmnD[n]) cmnD[n] = pkc; }
        }
      }
#pragma unroll
      for (int mk = 1; mk <= 8; mk <<= 1) {
        rmxS = fmaxf(rmxS, __shfl_xor(rmxS, mk));
        rmxD = fmaxf(rmxD, __shfl_xor(rmxD, mk));
        u64 o = shflx64(rmnS, mk); if (o < rmnS) rmnS = o;
        o = shflx64(rmnD, mk); if (o < rmnD) rmnD = o;
      }
      if (li == 0) {  // unique (wave,m,q,r) per row: single writer
        tab_mS[lr] = rmxS; tab_mD[lr] = rmxD;
        tab_nS[lr] = rmnS; tab_nD[lr] = rmnD;
      }
    }
#pragma unroll
  for (int n = 0; n < 8; ++n) {
#pragma unroll
    for (int mk = 16; mk <= 32; mk <<= 1) {
      cmxS[n] = fmaxf(cmxS[n], __shfl_xor(cmxS[n], mk));
      cmxD[n] = fmaxf(cmxD[n], __shfl_xor(cmxD[n], mk));
      u64 o = shflx64(cmnS[n], mk); if (o < cmnS[n]) cmnS[n] = o;
      o = shflx64(cmnD[n], mk); if (o < cmnD[n]) cmnD[n] = o;
    }
    if (lane < 16) {
      int lc = n * 16 + lane;
      int slot = 128 + lc * 2 + wave;
      tab_mS[slot] = cmxS[n]; tab_mD[slot] = cmxD[n];
      tab_nS[slot] = cmnS[n]; tab_nD[slot] = cmnD[n];
    }
  }
  __syncthreads();  // tables complete
  // commit: rows direct, cols pair-merged; coalesced, no atomics
  {
    size_t ob = (size_t)blockIdx.x * 256;
    PmS[ob + tid] = tab_mS[tid]; PmD[ob + tid] = tab_mD[tid];
    PnS[ob + tid] = tab_nS[tid]; PnD[ob + tid] = tab_nD[tid];
    float mS = fmaxf(tab_mS[128 + tid * 2], tab_mS[128 + tid * 2 + 1]);
    float mD = fmaxf(tab_mD[128 + tid * 2], tab_mD[128 + tid * 2 + 1]);
    u64 a = tab_nS[128 + tid * 2], b = tab_nS[128 + tid * 2 + 1]; u64 nS = a < b ? a : b;
    a = tab_nD[128 + tid * 2]; b = tab_nD[128 + tid * 2 + 1]; u64 nD = a < b ? a : b;
    PmS[ob + 128 + tid] = mS; PmD[ob + 128 + tid] = mD;
    PnS[ob + 128 + tid] = nS; PnD[ob + 128 + tid] = nD;
  }
}

// per-row merge of the 33 contributing tiles' partials -> per-row stats.
// Emits term12 (first two relu terms), mS, and the two gather indices.
__global__ void finstats_kernel(const float* __restrict__ PmS, const float* __restrict__ PmD,
                                const u64* __restrict__ PnS, const u64* __restrict__ PnD,
                                float* __restrict__ stP, float* __restrict__ stM,
                                int* __restrict__ stIA, int* __restrict__ stIB) {
  int r = blockIdx.x * 128 + threadIdx.x;
  int p = r >> 7, rl = r & 127;
  float mS = -1.f, mD = -1.f;
  u64 nS = ~0ull, nD = ~0ull;
  // row-side: tiles (p, t), t=p..31 are contiguous from g0 = base(p)
  int g0 = p * 32 - (p * (p - 1)) / 2;
  for (int t = 0; t < 32 - p; ++t) {
    size_t base = (size_t)(g0 + t) * 256 + rl;
    mS = fmaxf(mS, PmS[base]); mD = fmaxf(mD, PmD[base]);
    u64 a = PnS[base]; if (a < nS) nS = a;
    u64 b = PnD[base]; if (b < nD) nD = b;
  }
  // col-side: tiles (t, p), t=0..p; g(0,p)=p, g(t+1,p)=g(t,p)+(31-t)
  int gg = p;
  for (int t = 0; t <= p; ++t) {
    size_t base = (size_t)gg * 256 + 128 + rl;
    mS = fmaxf(mS, PmS[base]); mD = fmaxf(mD, PmD[base]);
    u64 a = PnS[base]; if (a < nS) nS = a;
    u64 b = PnD[base]; if (b < nD) nD = b;
    gg += 31 - t;
  }
  float mnSv = __uint_as_float((unsigned)(nS >> 32));
  float mnDv = __uint_as_float((unsigned)(nD >> 32));
  stP[r] = fmaxf(mS - mnSv + 0.8f, 0.f) + fmaxf(mD - mnDv + 0.5f, 0.f);
  stM[r] = mS;
  stIA[r] = (int)(nS & 0xffffffffull);
  stIB[r] = (int)(nD & 0xffffffffull);
}

// per-row: recompute dist[same_min_idx, dif_min_idx], accumulate the loss.
// 128 blocks x 32 rows; ONE same-address atomicAdd per block (G12).
__global__ void finloss_kernel(const unsigned short* __restrict__ Xb,
                               const float* __restrict__ sqv,
                               const float* __restrict__ stP, const float* __restrict__ stM,
                               const int* __restrict__ stIA, const int* __restrict__ stIB,
                               float* out) {
  int wave = threadIdx.x >> 6, lane = threadIdx.x & 63;
  float part = 0.f;
  for (int rr = 0; rr < 8; ++rr) {
    int row = blockIdx.x * 32 + wave * 8 + rr;
    int ia = stIA[row];  // same_min_idx (row of gather)
    int ib = stIB[row];  // dif_min_idx  (col of gather)
    const ushort4* pa = (const ushort4*)(Xb + (size_t)ia * DIM);
    const ushort4* pb = (const ushort4*)(Xb + (size_t)ib * DIM);
    float s = 0.f;
#pragma unroll
    for (int qq = 0; qq < 4; ++qq) {
      ushort4 a = pa[lane + qq * 64], b = pb[lane + qq * 64];
      s += bf2f(a.x) * bf2f(b.x) + bf2f(a.y) * bf2f(b.y) +
           bf2f(a.z) * bf2f(b.z) + bf2f(a.w) * bf2f(b.w);
    }
    for (int m = 32; m; m >>= 1) s += __shfl_xor(s, m);
    if (lane == 0) {
      float dneg = sqrtf(fmaxf(sqv[ia] + sqv[ib] - 2.f * s, 1e-12f));
      part += stP[row] + fmaxf(stM[row] - dneg + 0.3f, 0.f);
    }
  }
  __shared__ float wp[4];
  if (lane == 0) wp[wave] = part;
  __syncthreads();
  if (threadIdx.x == 0)
    atomicAdd(out, ((wp[0] + wp[1]) + (wp[2] + wp[3])) * (1.0f / 4096.0f));
}

extern "C" void kernel_launch(void* const* d_in, const int* in_sizes, int n_in,
                              void* d_out, int out_size, void* d_ws, size_t ws_size,
                              hipStream_t stream) {
  const float* X = (const float*)d_in[0];
  const int* tg  = (const int*)d_in[1];
  const int* fl  = (const int*)d_in[2];
  float* out = (float*)d_out;

  // workspace layout (~11.7 MB total)
  char* w = (char*)d_ws;
  unsigned short* Xb = (unsigned short*)(w);          // 8,388,608
  float* sqv = (float*)(w + 8388608);                 //    16,384
  float* PmS = (float*)(w + 8404992);                 //   540,672  (528*256*4)
  float* PmD = (float*)(w + 8945664);                 //   540,672
  u64*   PnS = (u64*)(w + 9486336);                   // 1,081,344  (528*256*8)
  u64*   PnD = (u64*)(w + 10567680);                  // 1,081,344
  float* stP = (float*)(w + 11649024);                //    16,384
  float* stM = (float*)(w + 11665408);                //    16,384
  int*   stIA = (int*)(w + 11681792);                 //    16,384
  int*   stIB = (int*)(w + 11698176);                 //    16,384

  prep_kernel<<<NROWS, 256, 0, stream>>>(X, Xb, sqv, out);
  gram_kernel<<<NT, 128, 0, stream>>>(Xb, sqv, tg, fl, PmS, PmD, PnS, PnD);
  finstats_kernel<<<32, 128, 0, stream>>>(PmS, PmD, PnS, PnD, stP, stM, stIA, stIB);
  finloss_kernel<<<128, 256, 0, stream>>>(Xb, sqv, stP, stM, stIA, stIB, out);
}

// Round 10
// 164.054 us; speedup vs baseline: 1.4932x; 1.4932x over previous
//
#include <hip/hip_runtime.h>

#define NROWS 4096
#define DIM   1024
#define NT    528   // triangular 32x32 tile grid

using f32x4 = __attribute__((ext_vector_type(4))) float;
using bfrag = __attribute__((ext_vector_type(8))) short;
typedef unsigned long long u64;

__device__ __forceinline__ unsigned short f2bf(float f) {
  unsigned u = __float_as_uint(f);
  u += 0x7fffu + ((u >> 16) & 1u);
  return (unsigned short)(u >> 16);
}
__device__ __forceinline__ float bf2f(unsigned short b) {
  return __uint_as_float(((unsigned)b) << 16);
}
__device__ __forceinline__ u64 shflx64(u64 v, int m) {
  int lo = __shfl_xor((int)(unsigned)(v & 0xffffffffull), m);
  int hi = __shfl_xor((int)(unsigned)(v >> 32), m);
  return ((u64)(unsigned)hi << 32) | (unsigned)lo;
}

// fp32 -> bf16 (RNE) + row squared-norms (+ out zero)
__global__ void prep_kernel(const float* __restrict__ X, unsigned short* __restrict__ Xb,
                            float* __restrict__ sqv, float* out) {
  int row = blockIdx.x, t = threadIdx.x;  // 256 threads, 4 floats each
  float4 v = reinterpret_cast<const float4*>(X + (size_t)row * DIM)[t];
  unsigned short b0 = f2bf(v.x), b1 = f2bf(v.y), b2 = f2bf(v.z), b3 = f2bf(v.w);
  float f0 = bf2f(b0), f1 = bf2f(b1), f2 = bf2f(b2), f3 = bf2f(b3);
  float s = f0 * f0 + f1 * f1 + f2 * f2 + f3 * f3;
  reinterpret_cast<ushort4*>(Xb + (size_t)row * DIM)[t] = make_ushort4(b0, b1, b2, b3);
  for (int m = 32; m; m >>= 1) s += __shfl_xor(s, m);
  __shared__ float ws4[4];
  if ((t & 63) == 0) ws4[t >> 6] = s;
  __syncthreads();
  if (t == 0) {
    sqv[row] = (ws4[0] + ws4[1]) + (ws4[2] + ws4[3]);
    if (row == 0) out[0] = 0.f;
  }
}

// Stage one BK=64 tile pair (A at smem, B at smem+16K). R2-proven pattern:
// each global_load_lds covers 8 contiguous rows x 128B (coalesced); k-slot XOR
// involution (rule 21: linear LDS dest, inverse-swizzled global source).
#define STAGE(KS)                                                                \
  {                                                                              \
    _Pragma("unroll")                                                            \
    for (int qq = 0; qq < 4; ++qq) {                                             \
      int boff = (wave * 4 + qq) * 1024;            /* 8 rows of 128B */         \
      int r = (wave * 4 + qq) * 8 + (lane >> 3);    /* row this lane fills */    \
      const unsigned short* sA = Xb + (size_t)(row0 + r) * DIM + (KS) + ksrc;    \
      __builtin_amdgcn_global_load_lds(                                          \
          (const __attribute__((address_space(1))) void*)sA,                     \
          (__attribute__((address_space(3))) void*)(smem + boff), 16, 0, 0);     \
      const unsigned short* sB = Xb + (size_t)(col0 + r) * DIM + (KS) + ksrc;    \
      __builtin_amdgcn_global_load_lds(                                          \
          (const __attribute__((address_space(1))) void*)sB,                     \
          (__attribute__((address_space(3))) void*)(smem + 16384 + boff), 16, 0, 0); \
    }                                                                            \
  }

// 128x128 bf16-MFMA Gram tile (triangular tm-major grid) + fused masked
// reductions. Shared single-buffer staging (R2/R6 K-loop), in-register
// epilogue, NO-atomic commit (R7): LDS single-writer tables -> coalesced P*
// stores. LDS ~35KB -> 4 blocks/CU -> ALL 528 blocks resident (no tail round).
__global__ __launch_bounds__(256) void gram_kernel(
    const unsigned short* __restrict__ Xb, const float* __restrict__ sqv,
    const int* __restrict__ tg, const int* __restrict__ fl,
    float* __restrict__ PmS, float* __restrict__ PmD,
    u64* __restrict__ PnS, u64* __restrict__ PnD) {
  __shared__ __attribute__((aligned(16))) char smem[32768];  // A 16K | B 16K; tabs alias
  __shared__ float srow[128], scol[128];
  __shared__ int rtagp[128], ctagp[128];

  // triangular decode (tm-major): tiles with tm <= tn; g == blockIdx.x
  int tm = 0, g = blockIdx.x, rem = 32;
  while (g >= rem) { g -= rem; rem--; tm++; }
  int tn = tm + g;
  const int row0 = tm * 128, col0 = tn * 128;
  const int tid = threadIdx.x;
  const int wave = tid >> 6, lane = tid & 63;
  const int q = lane >> 4, li = lane & 15;
  const int ksrc = ((lane & 7) ^ (lane >> 3)) * 8;  // staging source k-offset

  if (tid < 128) {
    srow[tid] = sqv[row0 + tid];
    rtagp[tid] = (fl[row0 + tid] << 12) | tg[row0 + tid];  // tg<1024, fl in {0,1}
  } else {
    int c = tid - 128;
    scol[c] = sqv[col0 + c];
    ctagp[c] = (fl[col0 + c] << 12) | tg[col0 + c];
  }

  unsigned short (*As)[64] = (unsigned short (*)[64])smem;
  unsigned short (*Bs)[64] = (unsigned short (*)[64])(smem + 16384);

  f32x4 acc[4][4] = {};
  const int wr = (wave >> 1) * 64, wc = (wave & 1) * 64;

  for (int ks = 0; ks < DIM; ks += 64) {
    __syncthreads();  // previous tile fully consumed (also orders tag fills)
    STAGE(ks);
    __syncthreads();  // staging complete
#pragma unroll
    for (int kk = 0; kk < 2; ++kk) {
      bfrag a[4], b[4];
      int kel = ((kk * 4 + q) ^ (lane & 7)) * 8;  // same k-map for A and B -> Gram safe
#pragma unroll
      for (int m = 0; m < 4; ++m)
        a[m] = *(const bfrag*)&As[wr + m * 16 + li][kel];
#pragma unroll
      for (int n = 0; n < 4; ++n)
        b[n] = *(const bfrag*)&Bs[wc + n * 16 + li][kel];
#pragma unroll
      for (int m = 0; m < 4; ++m)
#pragma unroll
        for (int n = 0; n < 4; ++n)
          acc[m][n] = __builtin_amdgcn_mfma_f32_16x16x32_bf16(a[m], b[n], acc[m][n], 0, 0, 0);
    }
  }
  __syncthreads();  // all K-loop LDS reads done before tables alias smem

  // LDS partial tables (single-writer slots, no atomics):
  // rows: slot = lr*2 + (wave&1)        [0, 256)
  // cols: slot = 256 + lc*2 + (wave>>1) [256, 512)
  float* tab_mS = (float*)smem;                 // 2 KB
  float* tab_mD = (float*)(smem + 2048);        // 2 KB
  u64*   tab_nS = (u64*)(smem + 4096);          // 4 KB
  u64*   tab_nD = (u64*)(smem + 8192);          // 4 KB

  // ---- in-register reductions (R6/R7-proven) ----
  float cmxS[4], cmxD[4];
  u64 cmnS[4], cmnD[4];
  int ctv[4]; float scv[4];
#pragma unroll
  for (int n = 0; n < 4; ++n) {
    cmxS[n] = -1.f; cmxD[n] = -1.f; cmnS[n] = ~0ull; cmnD[n] = ~0ull;
    int lc = wc + n * 16 + li; ctv[n] = ctagp[lc]; scv[n] = scol[lc];
  }
#pragma unroll
  for (int m = 0; m < 4; ++m)
#pragma unroll
    for (int r = 0; r < 4; ++r) {
      int lr = wr + m * 16 + q * 4 + r;   // C/D layout (m89-verified)
      int rt = rtagp[lr];
      float sr = srow[lr];
      u64 rbase = (unsigned)(row0 + lr);
      float rmxS = -1.f, rmxD = -1.f;
      u64 rmnS = ~0ull, rmnD = ~0ull;
#pragma unroll
      for (int n = 0; n < 4; ++n) {
        float d = sqrtf(fmaxf(sr + scv[n] - 2.0f * acc[m][n][r], 1e-12f));
        int x = rt ^ ctv[n];
        u64 db = (u64)__float_as_uint(d) << 32;
        u64 pkr = db | (unsigned)(col0 + wc + n * 16 + li);
        u64 pkc = db | rbase;
        if ((x & 0xFFF) == 0) {
          if ((x >> 12) == 0) { rmxS = fmaxf(rmxS, d); cmxS[n] = fmaxf(cmxS[n], d); }
          else                { rmxD = fmaxf(rmxD, d); cmxD[n] = fmaxf(cmxD[n], d); }
        } else {
          if ((x >> 12) == 0) { if (pkr < rmnS) rmnS = pkr; if (pkc < cmnS[n]) cmnS[n] = pkc; }
          else                { if (pkr < rmnD) rmnD = pkr; if (pkc < cmnD[n]) cmnD[n] = pkc; }
        }
      }
#pragma unroll
      for (int mk = 1; mk <= 8; mk <<= 1) {
        rmxS = fmaxf(rmxS, __shfl_xor(rmxS, mk));
        rmxD = fmaxf(rmxD, __shfl_xor(rmxD, mk));
        u64 o = shflx64(rmnS, mk); if (o < rmnS) rmnS = o;
        o = shflx64(rmnD, mk); if (o < rmnD) rmnD = o;
      }
      if (li == 0) {
        int slot = lr * 2 + (wave & 1);
        tab_mS[slot] = rmxS; tab_mD[slot] = rmxD;
        tab_nS[slot] = rmnS; tab_nD[slot] = rmnD;
      }
    }
#pragma unroll
  for (int n = 0; n < 4; ++n) {
#pragma unroll
    for (int mk = 16; mk <= 32; mk <<= 1) {
      cmxS[n] = fmaxf(cmxS[n], __shfl_xor(cmxS[n], mk));
      cmxD[n] = fmaxf(cmxD[n], __shfl_xor(cmxD[n], mk));
      u64 o = shflx64(cmnS[n], mk); if (o < cmnS[n]) cmnS[n] = o;
      o = shflx64(cmnD[n], mk); if (o < cmnD[n]) cmnD[n] = o;
    }
    if (lane < 16) {
      int lc = wc + n * 16 + lane;
      int slot = 256 + lc * 2 + (wave >> 1);
      tab_mS[slot] = cmxS[n]; tab_mD[slot] = cmxD[n];
      tab_nS[slot] = cmnS[n]; tab_nD[slot] = cmnD[n];
    }
  }
  __syncthreads();  // tables complete
  // merge the two halves per entry, store coalesced partials (no atomics)
  {
    int e = tid;  // 0..255: e<128 row e; e>=128 col e-128
    float mS = fmaxf(tab_mS[2 * e], tab_mS[2 * e + 1]);
    float mD = fmaxf(tab_mD[2 * e], tab_mD[2 * e + 1]);
    u64 a = tab_nS[2 * e], b = tab_nS[2 * e + 1]; u64 nS = a < b ? a : b;
    a = tab_nD[2 * e]; b = tab_nD[2 * e + 1]; u64 nD = a < b ? a : b;
    size_t o = (size_t)blockIdx.x * 256 + e;
    PmS[o] = mS; PmD[o] = mD; PnS[o] = nS; PnD[o] = nD;
  }
}

// per-row merge of the 33 contributing tiles' partials -> per-row stats.
// Emits term12 (first two relu terms), mS, and the two gather indices.
__global__ void finstats_kernel(const float* __restrict__ PmS, const float* __restrict__ PmD,
                                const u64* __restrict__ PnS, const u64* __restrict__ PnD,
                                float* __restrict__ stP, float* __restrict__ stM,
                                int* __restrict__ stIA, int* __restrict__ stIB) {
  int r = blockIdx.x * 128 + threadIdx.x;
  int p = r >> 7, rl = r & 127;
  float mS = -1.f, mD = -1.f;
  u64 nS = ~0ull, nD = ~0ull;
  // row-side: tiles (p, t), t=p..31 are contiguous from g0 = base(p)
  int g0 = p * 32 - (p * (p - 1)) / 2;
  for (int t = 0; t < 32 - p; ++t) {
    size_t base = (size_t)(g0 + t) * 256 + rl;
    mS = fmaxf(mS, PmS[base]); mD = fmaxf(mD, PmD[base]);
    u64 a = PnS[base]; if (a < nS) nS = a;
    u64 b = PnD[base]; if (b < nD) nD = b;
  }
  // col-side: tiles (t, p), t=0..p; g(0,p)=p, g(t+1,p)=g(t,p)+(31-t)
  int gg = p;
  for (int t = 0; t <= p; ++t) {
    size_t base = (size_t)gg * 256 + 128 + rl;
    mS = fmaxf(mS, PmS[base]); mD = fmaxf(mD, PmD[base]);
    u64 a = PnS[base]; if (a < nS) nS = a;
    u64 b = PnD[base]; if (b < nD) nD = b;
    gg += 31 - t;
  }
  float mnSv = __uint_as_float((unsigned)(nS >> 32));
  float mnDv = __uint_as_float((unsigned)(nD >> 32));
  stP[r] = fmaxf(mS - mnSv + 0.8f, 0.f) + fmaxf(mD - mnDv + 0.5f, 0.f);
  stM[r] = mS;
  stIA[r] = (int)(nS & 0xffffffffull);
  stIB[r] = (int)(nD & 0xffffffffull);
}

// per-row: recompute dist[same_min_idx, dif_min_idx], accumulate the loss.
// 128 blocks x 32 rows; ONE same-address atomicAdd per block (G12).
__global__ void finloss_kernel(const unsigned short* __restrict__ Xb,
                               const float* __restrict__ sqv,
                               const float* __restrict__ stP, const float* __restrict__ stM,
                               const int* __restrict__ stIA, const int* __restrict__ stIB,
                               float* out) {
  int wave = threadIdx.x >> 6, lane = threadIdx.x & 63;
  float part = 0.f;
  for (int rr = 0; rr < 8; ++rr) {
    int row = blockIdx.x * 32 + wave * 8 + rr;
    int ia = stIA[row];  // same_min_idx (row of gather)
    int ib = stIB[row];  // dif_min_idx  (col of gather)
    const ushort4* pa = (const ushort4*)(Xb + (size_t)ia * DIM);
    const ushort4* pb = (const ushort4*)(Xb + (size_t)ib * DIM);
    float s = 0.f;
#pragma unroll
    for (int qq = 0; qq < 4; ++qq) {
      ushort4 a = pa[lane + qq * 64], b = pb[lane + qq * 64];
      s += bf2f(a.x) * bf2f(b.x) + bf2f(a.y) * bf2f(b.y) +
           bf2f(a.z) * bf2f(b.z) + bf2f(a.w) * bf2f(b.w);
    }
    for (int m = 32; m; m >>= 1) s += __shfl_xor(s, m);
    if (lane == 0) {
      float dneg = sqrtf(fmaxf(sqv[ia] + sqv[ib] - 2.f * s, 1e-12f));
      part += stP[row] + fmaxf(stM[row] - dneg + 0.3f, 0.f);
    }
  }
  __shared__ float wp[4];
  if (lane == 0) wp[wave] = part;
  __syncthreads();
  if (threadIdx.x == 0)
    atomicAdd(out, ((wp[0] + wp[1]) + (wp[2] + wp[3])) * (1.0f / 4096.0f));
}

extern "C" void kernel_launch(void* const* d_in, const int* in_sizes, int n_in,
                              void* d_out, int out_size, void* d_ws, size_t ws_size,
                              hipStream_t stream) {
  const float* X = (const float*)d_in[0];
  const int* tg  = (const int*)d_in[1];
  const int* fl  = (const int*)d_in[2];
  float* out = (float*)d_out;

  // workspace layout (~11.7 MB total)
  char* w = (char*)d_ws;
  unsigned short* Xb = (unsigned short*)(w);          // 8,388,608
  float* sqv = (float*)(w + 8388608);                 //    16,384
  float* PmS = (float*)(w + 8404992);                 //   540,672  (528*256*4)
  float* PmD = (float*)(w + 8945664);                 //   540,672
  u64*   PnS = (u64*)(w + 9486336);                   // 1,081,344  (528*256*8)
  u64*   PnD = (u64*)(w + 10567680);                  // 1,081,344
  float* stP = (float*)(w + 11649024);                //    16,384
  float* stM = (float*)(w + 11665408);                //    16,384
  int*   stIA = (int*)(w + 11681792);                 //    16,384
  int*   stIB = (int*)(w + 11698176);                 //    16,384

  prep_kernel<<<NROWS, 256, 0, stream>>>(X, Xb, sqv, out);
  gram_kernel<<<NT, 256, 0, stream>>>(Xb, sqv, tg, fl, PmS, PmD, PnS, PnD);
  finstats_kernel<<<32, 128, 0, stream>>>(PmS, PmD, PnS, PnD, stP, stM, stIA, stIB);
  finloss_kernel<<<128, 256, 0, stream>>>(Xb, sqv, stP, stM, stIA, stIB, out);
}

// Round 11
// 159.424 us; speedup vs baseline: 1.5365x; 1.0290x over previous
//
#include <hip/hip_runtime.h>

#define NROWS 4096
#define DIM   1024
#define NT    528   // triangular 32x32 tile grid

using f32x4 = __attribute__((ext_vector_type(4))) float;
using bfrag = __attribute__((ext_vector_type(8))) short;
typedef unsigned long long u64;

__device__ __forceinline__ unsigned short f2bf(float f) {
  unsigned u = __float_as_uint(f);
  u += 0x7fffu + ((u >> 16) & 1u);
  return (unsigned short)(u >> 16);
}
__device__ __forceinline__ float bf2f(unsigned short b) {
  return __uint_as_float(((unsigned)b) << 16);
}
__device__ __forceinline__ u64 shflx64(u64 v, int m) {
  int lo = __shfl_xor((int)(unsigned)(v & 0xffffffffull), m);
  int hi = __shfl_xor((int)(unsigned)(v >> 32), m);
  return ((u64)(unsigned)hi << 32) | (unsigned)lo;
}

// fp32 -> bf16 (RNE) + row squared-norms (+ out zero)
__global__ void prep_kernel(const float* __restrict__ X, unsigned short* __restrict__ Xb,
                            float* __restrict__ sqv, float* out) {
  int row = blockIdx.x, t = threadIdx.x;  // 256 threads, 4 floats each
  float4 v = reinterpret_cast<const float4*>(X + (size_t)row * DIM)[t];
  unsigned short b0 = f2bf(v.x), b1 = f2bf(v.y), b2 = f2bf(v.z), b3 = f2bf(v.w);
  float f0 = bf2f(b0), f1 = bf2f(b1), f2 = bf2f(b2), f3 = bf2f(b3);
  float s = f0 * f0 + f1 * f1 + f2 * f2 + f3 * f3;
  reinterpret_cast<ushort4*>(Xb + (size_t)row * DIM)[t] = make_ushort4(b0, b1, b2, b3);
  for (int m = 32; m; m >>= 1) s += __shfl_xor(s, m);
  __shared__ float ws4[4];
  if ((t & 63) == 0) ws4[t >> 6] = s;
  __syncthreads();
  if (t == 0) {
    sqv[row] = (ws4[0] + ws4[1]) + (ws4[2] + ws4[3]);
    if (row == 0) out[0] = 0.f;
  }
}

// Stage one BK=128 tile pair (A [128][128] at smem, B at smem+32K).
// Each global_load_lds covers 4 contiguous rows x 256B; lanes permute 16B
// chunks WITHIN each aligned 256B segment (coalescing preserved). 4-bit k-slot
// XOR involution (rule 21): LDS[r][slot] holds global slot slot^(r&15);
// linear LDS dest, inverse-swizzled global source. 16 loads/wave/step ->
// 16KB in flight per wave at the drain (2x R10's depth).
#define STAGE(KS)                                                                \
  {                                                                              \
    _Pragma("unroll")                                                            \
    for (int jj = 0; jj < 8; ++jj) {                                             \
      int ch = wave * 8 + jj;                       /* chunk of 4 rows */        \
      int boff = ch * 1024;                                                      \
      int r = ch * 4 + (lane >> 4);                 /* row this lane fills */    \
      int sG = (((lane & 15) ^ (r & 15)) << 3);     /* global k-slot elems */    \
      const unsigned short* sA = Xb + (size_t)(row0 + r) * DIM + (KS) + sG;      \
      __builtin_amdgcn_global_load_lds(                                          \
          (const __attribute__((address_space(1))) void*)sA,                     \
          (__attribute__((address_space(3))) void*)(smem + boff), 16, 0, 0);     \
      const unsigned short* sB = Xb + (size_t)(col0 + r) * DIM + (KS) + sG;      \
      __builtin_amdgcn_global_load_lds(                                          \
          (const __attribute__((address_space(1))) void*)sB,                     \
          (__attribute__((address_space(3))) void*)(smem + 32768 + boff), 16, 0, 0); \
    }                                                                            \
  }

// 128x128 bf16-MFMA Gram tile (triangular tm-major grid), BK=128 (8 deep-wait
// K-steps) + fused masked reductions; NO-atomic commit via LDS single-writer
// tables -> coalesced P* stores (R7-proven).
__global__ __launch_bounds__(256) void gram_kernel(
    const unsigned short* __restrict__ Xb, const float* __restrict__ sqv,
    const int* __restrict__ tg, const int* __restrict__ fl,
    float* __restrict__ PmS, float* __restrict__ PmD,
    u64* __restrict__ PnS, u64* __restrict__ PnD) {
  __shared__ __attribute__((aligned(16))) char smem[65536];  // A 32K | B 32K; tabs alias
  __shared__ float srow[128], scol[128];
  __shared__ int rtagp[128], ctagp[128];

  // triangular decode (tm-major): tiles with tm <= tn; g == blockIdx.x
  int tm = 0, g = blockIdx.x, rem = 32;
  while (g >= rem) { g -= rem; rem--; tm++; }
  int tn = tm + g;
  const int row0 = tm * 128, col0 = tn * 128;
  const int tid = threadIdx.x;
  const int wave = tid >> 6, lane = tid & 63;
  const int q = lane >> 4, li = lane & 15;

  if (tid < 128) {
    srow[tid] = sqv[row0 + tid];
    rtagp[tid] = (fl[row0 + tid] << 12) | tg[row0 + tid];  // tg<1024, fl in {0,1}
  } else {
    int c = tid - 128;
    scol[c] = sqv[col0 + c];
    ctagp[c] = (fl[col0 + c] << 12) | tg[col0 + c];
  }

  unsigned short (*As)[128] = (unsigned short (*)[128])smem;
  unsigned short (*Bs)[128] = (unsigned short (*)[128])(smem + 32768);

  f32x4 acc[4][4] = {};
  const int wr = (wave >> 1) * 64, wc = (wave & 1) * 64;

  for (int ks = 0; ks < DIM; ks += 128) {
    __syncthreads();  // previous tile fully consumed (also orders tag fills)
    STAGE(ks);
    __syncthreads();  // staging complete (compiler drains vmcnt here)
#pragma unroll
    for (int kk = 0; kk < 4; ++kk) {
      bfrag a[4], b[4];
      // needed slot s = kk*4+q of row rA; stored at s ^ (rA&15), rA&15 == li.
      int kel = ((kk * 4 + q) ^ li) << 3;  // same k-map for A and B -> Gram safe
#pragma unroll
      for (int m = 0; m < 4; ++m)
        a[m] = *(const bfrag*)&As[wr + m * 16 + li][kel];
#pragma unroll
      for (int n = 0; n < 4; ++n)
        b[n] = *(const bfrag*)&Bs[wc + n * 16 + li][kel];
#pragma unroll
      for (int m = 0; m < 4; ++m)
#pragma unroll
        for (int n = 0; n < 4; ++n)
          acc[m][n] = __builtin_amdgcn_mfma_f32_16x16x32_bf16(a[m], b[n], acc[m][n], 0, 0, 0);
    }
  }
  __syncthreads();  // all K-loop LDS reads done before tables alias smem

  // LDS partial tables (single-writer slots, no atomics):
  // rows: slot = lr*2 + (wave&1)        [0, 256)
  // cols: slot = 256 + lc*2 + (wave>>1) [256, 512)
  float* tab_mS = (float*)smem;                 // 2 KB
  float* tab_mD = (float*)(smem + 2048);        // 2 KB
  u64*   tab_nS = (u64*)(smem + 4096);          // 4 KB
  u64*   tab_nD = (u64*)(smem + 8192);          // 4 KB

  // ---- in-register reductions (R6/R7-proven) ----
  float cmxS[4], cmxD[4];
  u64 cmnS[4], cmnD[4];
  int ctv[4]; float scv[4];
#pragma unroll
  for (int n = 0; n < 4; ++n) {
    cmxS[n] = -1.f; cmxD[n] = -1.f; cmnS[n] = ~0ull; cmnD[n] = ~0ull;
    int lc = wc + n * 16 + li; ctv[n] = ctagp[lc]; scv[n] = scol[lc];
  }
#pragma unroll
  for (int m = 0; m < 4; ++m)
#pragma unroll
    for (int r = 0; r < 4; ++r) {
      int lr = wr + m * 16 + q * 4 + r;   // C/D layout (m89-verified)
      int rt = rtagp[lr];
      float sr = srow[lr];
      u64 rbase = (unsigned)(row0 + lr);
      float rmxS = -1.f, rmxD = -1.f;
      u64 rmnS = ~0ull, rmnD = ~0ull;
#pragma unroll
      for (int n = 0; n < 4; ++n) {
        float d = sqrtf(fmaxf(sr + scv[n] - 2.0f * acc[m][n][r], 1e-12f));
        int x = rt ^ ctv[n];
        u64 db = (u64)__float_as_uint(d) << 32;
        u64 pkr = db | (unsigned)(col0 + wc + n * 16 + li);
        u64 pkc = db | rbase;
        if ((x & 0xFFF) == 0) {
          if ((x >> 12) == 0) { rmxS = fmaxf(rmxS, d); cmxS[n] = fmaxf(cmxS[n], d); }
          else                { rmxD = fmaxf(rmxD, d); cmxD[n] = fmaxf(cmxD[n], d); }
        } else {
          if ((x >> 12) == 0) { if (pkr < rmnS) rmnS = pkr; if (pkc < cmnS[n]) cmnS[n] = pkc; }
          else                { if (pkr < rmnD) rmnD = pkr; if (pkc < cmnD[n]) cmnD[n] = pkc; }
        }
      }
#pragma unroll
      for (int mk = 1; mk <= 8; mk <<= 1) {
        rmxS = fmaxf(rmxS, __shfl_xor(rmxS, mk));
        rmxD = fmaxf(rmxD, __shfl_xor(rmxD, mk));
        u64 o = shflx64(rmnS, mk); if (o < rmnS) rmnS = o;
        o = shflx64(rmnD, mk); if (o < rmnD) rmnD = o;
      }
      if (li == 0) {
        int slot = lr * 2 + (wave & 1);
        tab_mS[slot] = rmxS; tab_mD[slot] = rmxD;
        tab_nS[slot] = rmnS; tab_nD[slot] = rmnD;
      }
    }
#pragma unroll
  for (int n = 0; n < 4; ++n) {
#pragma unroll
    for (int mk = 16; mk <= 32; mk <<= 1) {
      cmxS[n] = fmaxf(cmxS[n], __shfl_xor(cmxS[n], mk));
      cmxD[n] = fmaxf(cmxD[n], __shfl_xor(cmxD[n], mk));
      u64 o = shflx64(cmnS[n], mk); if (o < cmnS[n]) cmnS[n] = o;
      o = shflx64(cmnD[n], mk); if (o < cmnD[n]) cmnD[n] = o;
    }
    if (lane < 16) {
      int lc = wc + n * 16 + lane;
      int slot = 256 + lc * 2 + (wave >> 1);
      tab_mS[slot] = cmxS[n]; tab_mD[slot] = cmxD[n];
      tab_nS[slot] = cmnS[n]; tab_nD[slot] = cmnD[n];
    }
  }
  __syncthreads();  // tables complete
  // merge the two halves per entry, store coalesced partials (no atomics)
  {
    int e = tid;  // 0..255: e<128 row e; e>=128 col e-128
    float mS = fmaxf(tab_mS[2 * e], tab_mS[2 * e + 1]);
    float mD = fmaxf(tab_mD[2 * e], tab_mD[2 * e + 1]);
    u64 a = tab_nS[2 * e], b = tab_nS[2 * e + 1]; u64 nS = a < b ? a : b;
    a = tab_nD[2 * e]; b = tab_nD[2 * e + 1]; u64 nD = a < b ? a : b;
    size_t o = (size_t)blockIdx.x * 256 + e;
    PmS[o] = mS; PmD[o] = mD; PnS[o] = nS; PnD[o] = nD;
  }
}

// per-row merge of the 33 contributing tiles' partials -> per-row stats.
// Emits term12 (first two relu terms), mS, and the two gather indices.
__global__ void finstats_kernel(const float* __restrict__ PmS, const float* __restrict__ PmD,
                                const u64* __restrict__ PnS, const u64* __restrict__ PnD,
                                float* __restrict__ stP, float* __restrict__ stM,
                                int* __restrict__ stIA, int* __restrict__ stIB) {
  int r = blockIdx.x * 128 + threadIdx.x;
  int p = r >> 7, rl = r & 127;
  float mS = -1.f, mD = -1.f;
  u64 nS = ~0ull, nD = ~0ull;
  // row-side: tiles (p, t), t=p..31 are contiguous from g0 = base(p)
  int g0 = p * 32 - (p * (p - 1)) / 2;
  for (int t = 0; t < 32 - p; ++t) {
    size_t base = (size_t)(g0 + t) * 256 + rl;
    mS = fmaxf(mS, PmS[base]); mD = fmaxf(mD, PmD[base]);
    u64 a = PnS[base]; if (a < nS) nS = a;
    u64 b = PnD[base]; if (b < nD) nD = b;
  }
  // col-side: tiles (t, p), t=0..p; g(0,p)=p, g(t+1,p)=g(t,p)+(31-t)
  int gg = p;
  for (int t = 0; t <= p; ++t) {
    size_t base = (size_t)gg * 256 + 128 + rl;
    mS = fmaxf(mS, PmS[base]); mD = fmaxf(mD, PmD[base]);
    u64 a = PnS[base]; if (a < nS) nS = a;
    u64 b = PnD[base]; if (b < nD) nD = b;
    gg += 31 - t;
  }
  float mnSv = __uint_as_float((unsigned)(nS >> 32));
  float mnDv = __uint_as_float((unsigned)(nD >> 32));
  stP[r] = fmaxf(mS - mnSv + 0.8f, 0.f) + fmaxf(mD - mnDv + 0.5f, 0.f);
  stM[r] = mS;
  stIA[r] = (int)(nS & 0xffffffffull);
  stIB[r] = (int)(nD & 0xffffffffull);
}

// per-row: recompute dist[same_min_idx, dif_min_idx], accumulate the loss.
// 128 blocks x 32 rows; ONE same-address atomicAdd per block (G12).
__global__ void finloss_kernel(const unsigned short* __restrict__ Xb,
                               const float* __restrict__ sqv,
                               const float* __restrict__ stP, const float* __restrict__ stM,
                               const int* __restrict__ stIA, const int* __restrict__ stIB,
                               float* out) {
  int wave = threadIdx.x >> 6, lane = threadIdx.x & 63;
  float part = 0.f;
  for (int rr = 0; rr < 8; ++rr) {
    int row = blockIdx.x * 32 + wave * 8 + rr;
    int ia = stIA[row];  // same_min_idx (row of gather)
    int ib = stIB[row];  // dif_min_idx  (col of gather)
    const ushort4* pa = (const ushort4*)(Xb + (size_t)ia * DIM);
    const ushort4* pb = (const ushort4*)(Xb + (size_t)ib * DIM);
    float s = 0.f;
#pragma unroll
    for (int qq = 0; qq < 4; ++qq) {
      ushort4 a = pa[lane + qq * 64], b = pb[lane + qq * 64];
      s += bf2f(a.x) * bf2f(b.x) + bf2f(a.y) * bf2f(b.y) +
           bf2f(a.z) * bf2f(b.z) + bf2f(a.w) * bf2f(b.w);
    }
    for (int m = 32; m; m >>= 1) s += __shfl_xor(s, m);
    if (lane == 0) {
      float dneg = sqrtf(fmaxf(sqv[ia] + sqv[ib] - 2.f * s, 1e-12f));
      part += stP[row] + fmaxf(stM[row] - dneg + 0.3f, 0.f);
    }
  }
  __shared__ float wp[4];
  if (lane == 0) wp[wave] = part;
  __syncthreads();
  if (threadIdx.x == 0)
    atomicAdd(out, ((wp[0] + wp[1]) + (wp[2] + wp[3])) * (1.0f / 4096.0f));
}

extern "C" void kernel_launch(void* const* d_in, const int* in_sizes, int n_in,
                              void* d_out, int out_size, void* d_ws, size_t ws_size,
                              hipStream_t stream) {
  const float* X = (const float*)d_in[0];
  const int* tg  = (const int*)d_in[1];
  const int* fl  = (const int*)d_in[2];
  float* out = (float*)d_out;

  // workspace layout (~11.7 MB total)
  char* w = (char*)d_ws;
  unsigned short* Xb = (unsigned short*)(w);          // 8,388,608
  float* sqv = (float*)(w + 8388608);                 //    16,384
  float* PmS = (float*)(w + 8404992);                 //   540,672  (528*256*4)
  float* PmD = (float*)(w + 8945664);                 //   540,672
  u64*   PnS = (u64*)(w + 9486336);                   // 1,081,344  (528*256*8)
  u64*   PnD = (u64*)(w + 10567680);                  // 1,081,344
  float* stP = (float*)(w + 11649024);                //    16,384
  float* stM = (float*)(w + 11665408);                //    16,384
  int*   stIA = (int*)(w + 11681792);                 //    16,384
  int*   stIB = (int*)(w + 11698176);                 //    16,384

  prep_kernel<<<NROWS, 256, 0, stream>>>(X, Xb, sqv, out);
  gram_kernel<<<NT, 256, 0, stream>>>(Xb, sqv, tg, fl, PmS, PmD, PnS, PnD);
  finstats_kernel<<<32, 128, 0, stream>>>(PmS, PmD, PnS, PnD, stP, stM, stIA, stIB);
  finloss_kernel<<<128, 256, 0, stream>>>(Xb, sqv, stP, stM, stIA, stIB, out);
}